// Round 5
// baseline (327.377 us; speedup 1.0000x reference)
//
#include <hip/hip_runtime.h>
#include <hip/hip_bf16.h>
#include <cstdint>

#define B_SZ   4096
#define F_SZ   30
#define D_SZ   128
#define P_SZ   435
#define BM     128
#define GP     4                      // fj per block (A-tile reuse)
#define NG     120                    // sum over fi of ceil((29-fi)/GP)
#define NBT    (B_SZ / BM)            // 32
#define FD     (F_SZ * D_SZ)          // 3840
#define FEMB_ELEMS (B_SZ * F_SZ * D_SZ)
#define W_ELEMS    (P_SZ * D_SZ * D_SZ)
#define GRID_MAIN  (NG * NBT)         // 3840 (multiple of 8)

typedef __bf16 bf16x8 __attribute__((ext_vector_type(8)));
typedef float  f32x4  __attribute__((ext_vector_type(4)));
typedef unsigned short u16x8 __attribute__((ext_vector_type(8)));
typedef unsigned short u16x4 __attribute__((ext_vector_type(4)));

__device__ __forceinline__ unsigned short f2bf(float x) {
    unsigned int u = __float_as_uint(x);
    u += 0x7fffu + ((u >> 16) & 1u);
    return (unsigned short)(u >> 16);
}
__device__ __forceinline__ float bf2f(unsigned short v) {
    return __uint_as_float(((unsigned int)v) << 16);
}
__device__ __forceinline__ void gl_lds16(const void* g, void* l) {
    __builtin_amdgcn_global_load_lds(
        (const __attribute__((address_space(1))) unsigned int*)g,
        (__attribute__((address_space(3))) unsigned int*)l, 16, 0, 0);
}

__global__ __launch_bounds__(256)
void cvt_bf16_kernel(const float* __restrict__ src,
                     unsigned short* __restrict__ dst, int n8) {
    int stride = gridDim.x * blockDim.x;
    for (int i = blockIdx.x * blockDim.x + threadIdx.x; i < n8; i += stride) {
        const float* s = src + (size_t)i * 8;
        f32x4 a = *reinterpret_cast<const f32x4*>(s);
        f32x4 b = *reinterpret_cast<const f32x4*>(s + 4);
        u16x8 v;
        v[0]=f2bf(a[0]); v[1]=f2bf(a[1]); v[2]=f2bf(a[2]); v[3]=f2bf(a[3]);
        v[4]=f2bf(b[0]); v[5]=f2bf(b[1]); v[6]=f2bf(b[2]); v[7]=f2bf(b[3]);
        *reinterpret_cast<u16x8*>(dst + (size_t)i * 8) = v;
    }
}

// block = (b-tile of 128, fi, group of <=4 fj). A staged once, W per fj.
// In-loop W re-stage is reg-staged (global->VGPR issued before compute,
// ds_write after barrier) -- no async global_load_lds inside the loop.
__global__ __launch_bounds__(256, 2)
void bilinear_kernel(const unsigned short* __restrict__ wsA,
                     const unsigned short* __restrict__ wsW,
                     float* __restrict__ out) {
    __shared__ unsigned short As[BM * D_SZ];     // 32 KB
    __shared__ unsigned short Ws[D_SZ * D_SZ];   // 32 KB

    const int orig = blockIdx.x;
    const int bid  = (orig & 7) * (GRID_MAIN / 8) + (orig >> 3);

    const int btile = bid & 31;
    const int m0    = btile * BM;
    int g = bid >> 5;            // 0..NG-1
    int fi = 0;
    for (;;) {
        int ng = (29 - fi + GP - 1) / GP;
        if (g < ng) break;
        g -= ng; ++fi;
    }
    const int fj0    = fi + 1 + g * GP;
    const int fj_end = (fj0 + GP < 30) ? (fj0 + GP) : 30;
    const int pbase  = 29 * fi - (fi * (fi - 1)) / 2 - fi - 1;  // p = pbase + fj

    const int tid  = threadIdx.x;
    const int lane = tid & 63;
    const int wave = tid >> 6;
    const int l16  = lane >> 4;
    const int lc   = lane & 15;

    // ---- prologue: stage A + W(fj0) via global_load_lds, swizzled source ----
    {
        const unsigned short* baseA = wsA + (size_t)m0 * FD + fi * D_SZ;
        #pragma unroll
        for (int it = 0; it < 8; ++it) {
            int r0 = wave * 32 + it * 4;
            int rl = r0 + l16;
            int cs = lc ^ (rl & 7);
            gl_lds16(baseA + (size_t)rl * FD + cs * 8, &As[r0 * 128]);
        }
        const unsigned short* baseW = wsW + (size_t)(pbase + fj0) * (D_SZ * D_SZ);
        #pragma unroll
        for (int it = 0; it < 8; ++it) {
            int r0 = wave * 32 + it * 4;
            int rl = r0 + l16;
            int cs = lc ^ (rl & 7);
            gl_lds16(baseW + rl * 128 + cs * 8, &Ws[r0 * 128]);
        }
    }
    __syncthreads();

    const int wb = (wave & 1) * 64;    // b-range (64) of this wave
    const int we = (wave >> 1) * 64;   // e-range (64) of this wave

    // ---- A fragments: loaded once, reused for all fj ----
    bf16x8 afr[4][4];
    #pragma unroll
    for (int m = 0; m < 4; ++m) {
        int bl = wb + m * 16 + lc;
        #pragma unroll
        for (int kk = 0; kk < 4; ++kk)
            afr[m][kk] = *reinterpret_cast<const bf16x8*>(
                &As[bl * 128 + (((kk * 4 + l16) ^ (bl & 7)) * 8)]);
    }

    for (int fj = fj0;;) {
        const int p = pbase + fj;
        const bool has_next = (fj + 1 < fj_end);   // block-uniform

        // ---- issue next-W global loads early: latency hides under MFMA ----
        u16x8 wreg[8];
        if (has_next) {
            const unsigned short* baseW = wsW + (size_t)(p + 1) * (D_SZ * D_SZ);
            #pragma unroll
            for (int it = 0; it < 8; ++it)
                wreg[it] = *reinterpret_cast<const u16x8*>(
                    baseW + (it * 256 + tid) * 8);
        }

        f32x4 acc[4][4];
        #pragma unroll
        for (int n = 0; n < 4; ++n)
            #pragma unroll
            for (int m = 0; m < 4; ++m) acc[n][m] = (f32x4)0.0f;

        #pragma unroll
        for (int n = 0; n < 4; ++n) {
            int el = we + n * 16 + lc;
            #pragma unroll
            for (int kk = 0; kk < 4; ++kk) {
                bf16x8 wfr = *reinterpret_cast<const bf16x8*>(
                    &Ws[el * 128 + (((kk * 4 + l16) ^ (el & 7)) * 8)]);
                #pragma unroll
                for (int m = 0; m < 4; ++m)
                    acc[n][m] = __builtin_amdgcn_mfma_f32_16x16x32_bf16(
                        wfr, afr[m][kk], acc[n][m], 0, 0, 0);
            }
        }

        // ---- epilogue: out[b,p,e] = acc * vj (bf16), non-temporal stores ----
        #pragma unroll
        for (int m = 0; m < 4; ++m) {
            int b = m0 + wb + m * 16 + lc;
            const unsigned short* vjrow = wsA + (size_t)b * FD + fj * D_SZ;
            float* orow = out + ((size_t)b * P_SZ + p) * D_SZ;
            #pragma unroll
            for (int n = 0; n < 4; ++n) {
                int e0 = we + n * 16 + l16 * 4;
                u16x4 vjb = *reinterpret_cast<const u16x4*>(vjrow + e0);
                f32x4 r;
                r[0] = acc[n][m][0] * bf2f(vjb[0]);
                r[1] = acc[n][m][1] * bf2f(vjb[1]);
                r[2] = acc[n][m][2] * bf2f(vjb[2]);
                r[3] = acc[n][m][3] * bf2f(vjb[3]);
                __builtin_nontemporal_store(r, reinterpret_cast<f32x4*>(orow + e0));
            }
        }

        if (!has_next) break;

        __syncthreads();   // all waves done reading Ws (compiler drains lgkm)
        // ---- write next W into Ws; plain ds_write is barrier-ordered ----
        #pragma unroll
        for (int it = 0; it < 8; ++it) {
            int cl  = it * 256 + tid;
            int row = cl >> 4;
            int c   = cl & 15;
            *reinterpret_cast<u16x8*>(
                &Ws[row * 128 + ((c ^ (row & 7)) * 8)]) = wreg[it];
        }
        __syncthreads();   // Ws ready
        ++fj;
    }
}

extern "C" void kernel_launch(void* const* d_in, const int* in_sizes, int n_in,
                              void* d_out, int out_size, void* d_ws, size_t ws_size,
                              hipStream_t stream) {
    const float* femb = (const float*)d_in[0];
    const float* W    = (const float*)d_in[1];
    float* out        = (float*)d_out;

    unsigned short* wsA = (unsigned short*)d_ws;
    unsigned short* wsW = wsA + FEMB_ELEMS;

    hipLaunchKernelGGL(cvt_bf16_kernel, dim3(2048), dim3(256), 0, stream,
                       femb, wsA, FEMB_ELEMS / 8);
    hipLaunchKernelGGL(cvt_bf16_kernel, dim3(2048), dim3(256), 0, stream,
                       W, wsW, W_ELEMS / 8);
    hipLaunchKernelGGL(bilinear_kernel, dim3(GRID_MAIN), dim3(256), 0, stream,
                       wsA, wsW, out);
}